// Round 11
// baseline (56.691 us; speedup 1.0000x reference)
//
#include <hip/hip_runtime.h>

// SimpleGNN: B=4, N=512, D=128, L=2 — 3 dispatches.
// msg[b,i,:] = (sum_j adj[b,i,j]*relu(ai'[b,i,:]+aj[b,j,:])) @ w2^T
//            + (sum_j adj[b,i,j]) * b2 ;  ai' = h@wi^T + b1, aj = h@wj^T
// Round-9 verified structure (50.7us) + (a) no weight-transpose dispatch:
// GEMVs read w1/w2 in natural [o][d] layout, one 128B line per (thread,slice);
// (b) adjsT[j][4] staging: inner iter = 1 float4 VMEM (2 j's) + 1 broadcast
// ds_read_b128 (4 rows' masks) + 48 FMA.

constexpr int Bc = 4, Nc = 512, Dc = 128, Lc = 2;
constexpr int BN = Bc * Nc;  // 2048
constexpr int TIB = 4;       // rows per msgfull block
constexpr int TN = 4;        // rows per lin block

// --- first linear, direct w1 reads: ai = h@wi^T + b1 ; aj = h@wj^T
__global__ __launch_bounds__(128) void gnn_lin1(const float* __restrict__ h,
                                                const float* __restrict__ w1,
                                                const float* __restrict__ b1,
                                                float* __restrict__ ai,
                                                float* __restrict__ aj) {
    __shared__ float hs[TN][Dc];
    const int o = threadIdx.x;
    const int r0 = blockIdx.x * TN;
#pragma unroll
    for (int t = 0; t < TN; ++t) hs[t][o] = h[(size_t)(r0 + t) * Dc + o];
    __syncthreads();
    float acci[TN], accj[TN];
    const float bo = b1[o];
#pragma unroll
    for (int t = 0; t < TN; ++t) { acci[t] = bo; accj[t] = 0.f; }
    const float* __restrict__ w1row = w1 + (size_t)o * (2 * Dc);
    for (int d = 0; d < Dc; d += 4) {
        const float4 wi = *reinterpret_cast<const float4*>(&w1row[d]);
        const float4 wj = *reinterpret_cast<const float4*>(&w1row[Dc + d]);
#pragma unroll
        for (int t = 0; t < TN; ++t) {
            const float4 hv = *reinterpret_cast<const float4*>(&hs[t][d]);
            acci[t] = fmaf(hv.x, wi.x, acci[t]);
            acci[t] = fmaf(hv.y, wi.y, acci[t]);
            acci[t] = fmaf(hv.z, wi.z, acci[t]);
            acci[t] = fmaf(hv.w, wi.w, acci[t]);
            accj[t] = fmaf(hv.x, wj.x, accj[t]);
            accj[t] = fmaf(hv.y, wj.y, accj[t]);
            accj[t] = fmaf(hv.z, wj.z, accj[t]);
            accj[t] = fmaf(hv.w, wj.w, accj[t]);
        }
    }
#pragma unroll
    for (int t = 0; t < TN; ++t) {
        ai[(size_t)(r0 + t) * Dc + o] = acci[t];
        aj[(size_t)(r0 + t) * Dc + o] = accj[t];
    }
}

// --- fused msg + lin2 + residual (+ lin1 of next layer), direct weight reads.
// grid = BN/TIB = 512 blocks, 512 thr (8 waves). Wave w streams j in
// [w*64, w*64+64) as 32 float4 loads (2 j's each).
template <bool HAS_NEXT>
__global__ __launch_bounds__(512) void gnn_msgfull(
    const float* __restrict__ ai, const float* __restrict__ aj,
    const float* __restrict__ adj, const float* __restrict__ hin,
    const float* __restrict__ w2, const float* __restrict__ b2,
    const float* __restrict__ w1n, const float* __restrict__ b1n,
    float* __restrict__ hout, float* __restrict__ ai_out,
    float* __restrict__ aj_out) {
    __shared__ __align__(16) float adjsT[Nc][TIB];  // 8 KB  [j][r]
    __shared__ __align__(16) float scratch[4096];   // 16 KB
    __shared__ float s_lds[TIB][Dc];                // 2 KB
    __shared__ float hnew_lds[TIB][Dc];             // 2 KB
    __shared__ float redw[8][TIB];
    __shared__ float arow_l[TIB];

    const int tid = threadIdx.x;
    const int w = tid >> 6;
    const int lane = tid & 63;
    const int r0 = blockIdx.x * TIB;
    const int b = r0 >> 9;        // / Nc
    const int i0 = r0 & (Nc - 1);
    const float* __restrict__ ajb = aj + (size_t)b * Nc * Dc;
    const float* __restrict__ adjb = adj + (size_t)b * Nc * Nc;

    // ---- stage adjsT[j][r]: thread = column j (coalesced row reads, b128 write)
    {
        float av[TIB];
#pragma unroll
        for (int r = 0; r < TIB; ++r) av[r] = adjb[(size_t)(i0 + r) * Nc + tid];
        *reinterpret_cast<float4*>(&adjsT[tid][0]) =
            make_float4(av[0], av[1], av[2], av[3]);
#pragma unroll
        for (int r = 0; r < TIB; ++r) {
            float p = av[r];
#pragma unroll
            for (int m = 32; m >= 1; m >>= 1) p += __shfl_xor(p, m);
            if (lane == 0) redw[w][r] = p;
        }
    }

    // ---- per-lane stream state: j-parity jlane, d-quad dq
    const int jlane = lane >> 5;
    const int dq = (lane & 31) * 4;
    float4 x[TIB], acc[TIB];
#pragma unroll
    for (int r = 0; r < TIB; ++r) {
        x[r] = *reinterpret_cast<const float4*>(&ai[(size_t)(r0 + r) * Dc + dq]);
        acc[r] = make_float4(0.f, 0.f, 0.f, 0.f);
    }
    __syncthreads();

    // ---- stream: 32 iters x (1 float4 VMEM + 1 b128 broadcast + 48 VALU)
    const int jw = w * 64;
    const float* __restrict__ pbase = ajb + (size_t)(jw + jlane) * Dc + dq;
#pragma unroll 4
    for (int it = 0; it < 32; ++it) {
        const float4 v =
            *reinterpret_cast<const float4*>(pbase + (size_t)it * 2 * Dc);
        const float4 a4 =
            *reinterpret_cast<const float4*>(&adjsT[jw + 2 * it + jlane][0]);
#define ROWF(r, a)                                                       \
        acc[r].x = fmaf(a, fmaxf(x[r].x + v.x, 0.f), acc[r].x);          \
        acc[r].y = fmaf(a, fmaxf(x[r].y + v.y, 0.f), acc[r].y);          \
        acc[r].z = fmaf(a, fmaxf(x[r].z + v.z, 0.f), acc[r].z);          \
        acc[r].w = fmaf(a, fmaxf(x[r].w + v.w, 0.f), acc[r].w);
        ROWF(0, a4.x) ROWF(1, a4.y) ROWF(2, a4.z) ROWF(3, a4.w)
#undef ROWF
    }

    // ---- merge j-parity halves; park per-wave partials
#pragma unroll
    for (int r = 0; r < TIB; ++r) {
        acc[r].x += __shfl_xor(acc[r].x, 32);
        acc[r].y += __shfl_xor(acc[r].y, 32);
        acc[r].z += __shfl_xor(acc[r].z, 32);
        acc[r].w += __shfl_xor(acc[r].w, 32);
    }
    if (lane < 32) {
#pragma unroll
        for (int r = 0; r < TIB; ++r)
            *reinterpret_cast<float4*>(&scratch[w * 512 + r * 128 + dq]) = acc[r];
    }
    __syncthreads();

    // ---- reduce 8 wave partials -> s_lds; arow
    {
        const int rr = tid >> 7;
        const int dd = tid & 127;
        float s = 0.f;
#pragma unroll
        for (int ww = 0; ww < 8; ++ww) s += scratch[ww * 512 + rr * 128 + dd];
        s_lds[rr][dd] = s;
    }
    if (tid < TIB) {
        float p = 0.f;
#pragma unroll
        for (int ww = 0; ww < 8; ++ww) p += redw[ww][tid];
        arow_l[tid] = p;
    }
    __syncthreads();

    // ---- lin2 GEMV, d-sliced, direct w2 reads (thread o owns one 128B line/slice)
    {
        const int o = tid & 127;
        const int g = tid >> 7;
        const float* __restrict__ w2row = w2 + (size_t)o * Dc;
        float part[TIB] = {0.f, 0.f, 0.f, 0.f};
        for (int dd = g * 32; dd < g * 32 + 32; dd += 4) {
            const float4 wv = *reinterpret_cast<const float4*>(&w2row[dd]);
#pragma unroll
            for (int r = 0; r < TIB; ++r) {
                const float4 sv = *reinterpret_cast<const float4*>(&s_lds[r][dd]);
                part[r] = fmaf(sv.x, wv.x, part[r]);
                part[r] = fmaf(sv.y, wv.y, part[r]);
                part[r] = fmaf(sv.z, wv.z, part[r]);
                part[r] = fmaf(sv.w, wv.w, part[r]);
            }
        }
#pragma unroll
        for (int r = 0; r < TIB; ++r) scratch[g * 512 + r * 128 + o] = part[r];
    }
    __syncthreads();

    // ---- combine + residual + b2*arow -> hnew
    {
        const int rr = tid >> 7;
        const int o = tid & 127;
        float a2c = scratch[rr * 128 + o] + scratch[512 + rr * 128 + o] +
                    scratch[1024 + rr * 128 + o] + scratch[1536 + rr * 128 + o];
        const float hn =
            hin[(size_t)(r0 + rr) * Dc + o] + a2c + arow_l[rr] * b2[o];
        hout[(size_t)(r0 + rr) * Dc + o] = hn;
        if constexpr (HAS_NEXT) hnew_lds[rr][o] = hn;
    }

    if constexpr (HAS_NEXT) {
        __syncthreads();
        // ---- lin1 of next layer, d-sliced, direct w1 reads
        {
            const int o = tid & 127;
            const int g = tid >> 7;
            const float* __restrict__ w1row = w1n + (size_t)o * (2 * Dc);
            float pi[TIB] = {0.f, 0.f, 0.f, 0.f};
            float pj[TIB] = {0.f, 0.f, 0.f, 0.f};
            for (int dd = g * 32; dd < g * 32 + 32; dd += 4) {
                const float4 wiv = *reinterpret_cast<const float4*>(&w1row[dd]);
                const float4 wjv =
                    *reinterpret_cast<const float4*>(&w1row[Dc + dd]);
#pragma unroll
                for (int r = 0; r < TIB; ++r) {
                    const float4 hv =
                        *reinterpret_cast<const float4*>(&hnew_lds[r][dd]);
                    pi[r] = fmaf(hv.x, wiv.x, pi[r]);
                    pi[r] = fmaf(hv.y, wiv.y, pi[r]);
                    pi[r] = fmaf(hv.z, wiv.z, pi[r]);
                    pi[r] = fmaf(hv.w, wiv.w, pi[r]);
                    pj[r] = fmaf(hv.x, wjv.x, pj[r]);
                    pj[r] = fmaf(hv.y, wjv.y, pj[r]);
                    pj[r] = fmaf(hv.z, wjv.z, pj[r]);
                    pj[r] = fmaf(hv.w, wjv.w, pj[r]);
                }
            }
#pragma unroll
            for (int r = 0; r < TIB; ++r) {
                scratch[g * 512 + r * 128 + o] = pi[r];
                scratch[2048 + g * 512 + r * 128 + o] = pj[r];
            }
        }
        __syncthreads();
        {
            const int rr = tid >> 7;
            const int o = tid & 127;
            float acci = b1n[o];
            float accj = 0.f;
#pragma unroll
            for (int g = 0; g < 4; ++g) {
                acci += scratch[g * 512 + rr * 128 + o];
                accj += scratch[2048 + g * 512 + rr * 128 + o];
            }
            ai_out[(size_t)(r0 + rr) * Dc + o] = acci;
            aj_out[(size_t)(r0 + rr) * Dc + o] = accj;
        }
    }
}

extern "C" void kernel_launch(void* const* d_in, const int* in_sizes, int n_in,
                              void* d_out, int out_size, void* d_ws, size_t ws_size,
                              hipStream_t stream) {
    const float* node = (const float*)d_in[0];
    const float* adj  = (const float*)d_in[1];
    const float* w1   = (const float*)d_in[2];
    const float* b1   = (const float*)d_in[3];
    const float* w2   = (const float*)d_in[4];
    const float* b2   = (const float*)d_in[5];
    float* out = (float*)d_out;

    float* ws = (float*)d_ws;
    float* ai  = ws; ws += BN * Dc;
    float* aj  = ws; ws += BN * Dc;
    float* ai2 = ws; ws += BN * Dc;
    float* aj2 = ws; ws += BN * Dc;
    float* h1  = ws; ws += BN * Dc;

    // layer 0
    gnn_lin1<<<BN / TN, 128, 0, stream>>>(node, w1, b1, ai, aj);
    gnn_msgfull<true><<<BN / TIB, 512, 0, stream>>>(
        ai, aj, adj, node, w2, b2, w1 + Dc * 2 * Dc, b1 + Dc, h1, ai2, aj2);
    // layer 1
    gnn_msgfull<false><<<BN / TIB, 512, 0, stream>>>(
        ai2, aj2, adj, h1, w2 + Dc * Dc, b2 + Dc, nullptr, nullptr, out,
        nullptr, nullptr);
}

// Round 12
// 55.068 us; speedup vs baseline: 1.0295x; 1.0295x over previous
//
#include <hip/hip_runtime.h>

// SimpleGNN: B=4, N=512, D=128, L=2 — 4 dispatches (round-9 structure).
// msg[b,i,:] = (sum_j adj[b,i,j]*relu(ai'[b,i,:]+aj[b,j,:])) @ w2^T
//            + (sum_j adj[b,i,j]) * b2 ;  ai' = h@wi^T + b1, aj = h@wj^T
// Delta vs round 9 (50.7us): adjsT[j][4] staging -> stream iter reads all 4
// rows' masks with ONE broadcast ds_read_b128 (was 4x b32). Weights read via
// transposed copies (coalesced) — round-11's natural-layout reads were an 8x
// transaction regression.

constexpr int Bc = 4, Nc = 512, Dc = 128, Lc = 2;
constexpr int BN = Bc * Nc;  // 2048
constexpr int TIB = 4;       // rows per msgfull block
constexpr int TN = 4;        // rows per lin block

// --- weight transpose: wiT[l][d][o], wjT[l][d][o], w2T[l][d][o]
__global__ void transpose_w_kernel(const float* __restrict__ w1,
                                   const float* __restrict__ w2,
                                   float* __restrict__ wiT,
                                   float* __restrict__ wjT,
                                   float* __restrict__ w2T) {
    int idx = blockIdx.x * blockDim.x + threadIdx.x;
    if (idx >= Lc * Dc * Dc) return;
    int l = idx / (Dc * Dc);
    int rem = idx - l * Dc * Dc;
    int d = rem / Dc;
    int o = rem - d * Dc;
    wiT[idx] = w1[(l * Dc + o) * (2 * Dc) + d];
    wjT[idx] = w1[(l * Dc + o) * (2 * Dc) + Dc + d];
    w2T[idx] = w2[(l * Dc + o) * Dc + d];
}

// --- first linear (round-3/9 winner, coalesced wiT/wjT reads)
__global__ __launch_bounds__(128) void gnn_lin1(const float* __restrict__ h,
                                                const float* __restrict__ wiT,
                                                const float* __restrict__ wjT,
                                                const float* __restrict__ b1,
                                                float* __restrict__ ai,
                                                float* __restrict__ aj) {
    __shared__ float hs[TN][Dc];
    const int o = threadIdx.x;
    const int r0 = blockIdx.x * TN;
#pragma unroll
    for (int t = 0; t < TN; ++t) hs[t][o] = h[(size_t)(r0 + t) * Dc + o];
    __syncthreads();
    float acci[TN], accj[TN];
    const float bo = b1[o];
#pragma unroll
    for (int t = 0; t < TN; ++t) { acci[t] = bo; accj[t] = 0.f; }
    for (int d = 0; d < Dc; d += 4) {
        float wi[4], wj[4];
#pragma unroll
        for (int k = 0; k < 4; ++k) {
            wi[k] = wiT[(size_t)(d + k) * Dc + o];
            wj[k] = wjT[(size_t)(d + k) * Dc + o];
        }
#pragma unroll
        for (int t = 0; t < TN; ++t) {
            const float4 hv = *reinterpret_cast<const float4*>(&hs[t][d]);
            acci[t] = fmaf(hv.x, wi[0], acci[t]);
            acci[t] = fmaf(hv.y, wi[1], acci[t]);
            acci[t] = fmaf(hv.z, wi[2], acci[t]);
            acci[t] = fmaf(hv.w, wi[3], acci[t]);
            accj[t] = fmaf(hv.x, wj[0], accj[t]);
            accj[t] = fmaf(hv.y, wj[1], accj[t]);
            accj[t] = fmaf(hv.z, wj[2], accj[t]);
            accj[t] = fmaf(hv.w, wj[3], accj[t]);
        }
    }
#pragma unroll
    for (int t = 0; t < TN; ++t) {
        ai[(size_t)(r0 + t) * Dc + o] = acci[t];
        aj[(size_t)(r0 + t) * Dc + o] = accj[t];
    }
}

// --- fused msg + lin2 + residual (+ lin1 of next layer).
// grid = BN/TIB = 512 blocks, 512 thr (8 waves). Wave w streams j in
// [w*64, w*64+64) as 32 float4 loads (2 j's each).
template <bool HAS_NEXT>
__global__ __launch_bounds__(512) void gnn_msgfull(
    const float* __restrict__ ai, const float* __restrict__ aj,
    const float* __restrict__ adj, const float* __restrict__ hin,
    const float* __restrict__ w2T, const float* __restrict__ b2,
    const float* __restrict__ wiT, const float* __restrict__ wjT,
    const float* __restrict__ b1n, float* __restrict__ hout,
    float* __restrict__ ai_out, float* __restrict__ aj_out) {
    __shared__ __align__(16) float adjsT[Nc][TIB];  // 8 KB  [j][r]
    __shared__ __align__(16) float scratch[4096];   // 16 KB
    __shared__ float s_lds[TIB][Dc];                // 2 KB
    __shared__ float hnew_lds[TIB][Dc];             // 2 KB
    __shared__ float redw[8][TIB];
    __shared__ float arow_l[TIB];

    const int tid = threadIdx.x;
    const int w = tid >> 6;
    const int lane = tid & 63;
    const int r0 = blockIdx.x * TIB;
    const int b = r0 >> 9;        // / Nc
    const int i0 = r0 & (Nc - 1);
    const float* __restrict__ ajb = aj + (size_t)b * Nc * Dc;
    const float* __restrict__ adjb = adj + (size_t)b * Nc * Nc;

    // ---- stage adjsT[j][r]: thread = column j (coalesced row reads, b128 write)
    {
        float av[TIB];
#pragma unroll
        for (int r = 0; r < TIB; ++r) av[r] = adjb[(size_t)(i0 + r) * Nc + tid];
        *reinterpret_cast<float4*>(&adjsT[tid][0]) =
            make_float4(av[0], av[1], av[2], av[3]);
#pragma unroll
        for (int r = 0; r < TIB; ++r) {
            float p = av[r];
#pragma unroll
            for (int m = 32; m >= 1; m >>= 1) p += __shfl_xor(p, m);
            if (lane == 0) redw[w][r] = p;
        }
    }

    // ---- per-lane stream state: j-parity jlane, d-quad dq
    const int jlane = lane >> 5;
    const int dq = (lane & 31) * 4;
    float4 x[TIB], acc[TIB];
#pragma unroll
    for (int r = 0; r < TIB; ++r) {
        x[r] = *reinterpret_cast<const float4*>(&ai[(size_t)(r0 + r) * Dc + dq]);
        acc[r] = make_float4(0.f, 0.f, 0.f, 0.f);
    }
    __syncthreads();

    // ---- stream: 32 iters x (1 float4 VMEM + 1 b128 broadcast + 48 VALU)
    const int jw = w * 64;
    const float* __restrict__ pbase = ajb + (size_t)(jw + jlane) * Dc + dq;
#pragma unroll 4
    for (int it = 0; it < 32; ++it) {
        const float4 v =
            *reinterpret_cast<const float4*>(pbase + (size_t)it * 2 * Dc);
        const float4 a4 =
            *reinterpret_cast<const float4*>(&adjsT[jw + 2 * it + jlane][0]);
#define ROWF(r, a)                                                       \
        acc[r].x = fmaf(a, fmaxf(x[r].x + v.x, 0.f), acc[r].x);          \
        acc[r].y = fmaf(a, fmaxf(x[r].y + v.y, 0.f), acc[r].y);          \
        acc[r].z = fmaf(a, fmaxf(x[r].z + v.z, 0.f), acc[r].z);          \
        acc[r].w = fmaf(a, fmaxf(x[r].w + v.w, 0.f), acc[r].w);
        ROWF(0, a4.x) ROWF(1, a4.y) ROWF(2, a4.z) ROWF(3, a4.w)
#undef ROWF
    }

    // ---- merge j-parity halves; park per-wave partials
#pragma unroll
    for (int r = 0; r < TIB; ++r) {
        acc[r].x += __shfl_xor(acc[r].x, 32);
        acc[r].y += __shfl_xor(acc[r].y, 32);
        acc[r].z += __shfl_xor(acc[r].z, 32);
        acc[r].w += __shfl_xor(acc[r].w, 32);
    }
    if (lane < 32) {
#pragma unroll
        for (int r = 0; r < TIB; ++r)
            *reinterpret_cast<float4*>(&scratch[w * 512 + r * 128 + dq]) = acc[r];
    }
    __syncthreads();

    // ---- reduce 8 wave partials -> s_lds; arow
    {
        const int rr = tid >> 7;
        const int dd = tid & 127;
        float s = 0.f;
#pragma unroll
        for (int ww = 0; ww < 8; ++ww) s += scratch[ww * 512 + rr * 128 + dd];
        s_lds[rr][dd] = s;
    }
    if (tid < TIB) {
        float p = 0.f;
#pragma unroll
        for (int ww = 0; ww < 8; ++ww) p += redw[ww][tid];
        arow_l[tid] = p;
    }
    __syncthreads();

    // ---- lin2 GEMV, d-sliced, coalesced w2T reads
    {
        const int o = tid & 127;
        const int g = tid >> 7;
        float part[TIB] = {0.f, 0.f, 0.f, 0.f};
        for (int dd = g * 32; dd < g * 32 + 32; dd += 4) {
            float wv[4];
#pragma unroll
            for (int k = 0; k < 4; ++k) wv[k] = w2T[(size_t)(dd + k) * Dc + o];
#pragma unroll
            for (int r = 0; r < TIB; ++r) {
                const float4 sv = *reinterpret_cast<const float4*>(&s_lds[r][dd]);
                part[r] = fmaf(sv.x, wv[0], part[r]);
                part[r] = fmaf(sv.y, wv[1], part[r]);
                part[r] = fmaf(sv.z, wv[2], part[r]);
                part[r] = fmaf(sv.w, wv[3], part[r]);
            }
        }
#pragma unroll
        for (int r = 0; r < TIB; ++r) scratch[g * 512 + r * 128 + o] = part[r];
    }
    __syncthreads();

    // ---- combine + residual + b2*arow -> hnew
    {
        const int rr = tid >> 7;
        const int o = tid & 127;
        float a2c = scratch[rr * 128 + o] + scratch[512 + rr * 128 + o] +
                    scratch[1024 + rr * 128 + o] + scratch[1536 + rr * 128 + o];
        const float hn =
            hin[(size_t)(r0 + rr) * Dc + o] + a2c + arow_l[rr] * b2[o];
        hout[(size_t)(r0 + rr) * Dc + o] = hn;
        if constexpr (HAS_NEXT) hnew_lds[rr][o] = hn;
    }

    if constexpr (HAS_NEXT) {
        __syncthreads();
        // ---- lin1 of next layer, d-sliced, coalesced wiT/wjT reads
        {
            const int o = tid & 127;
            const int g = tid >> 7;
            float pi[TIB] = {0.f, 0.f, 0.f, 0.f};
            float pj[TIB] = {0.f, 0.f, 0.f, 0.f};
            for (int dd = g * 32; dd < g * 32 + 32; dd += 4) {
                float wiv[4], wjv[4];
#pragma unroll
                for (int k = 0; k < 4; ++k) {
                    wiv[k] = wiT[(size_t)(dd + k) * Dc + o];
                    wjv[k] = wjT[(size_t)(dd + k) * Dc + o];
                }
#pragma unroll
                for (int r = 0; r < TIB; ++r) {
                    const float4 hv =
                        *reinterpret_cast<const float4*>(&hnew_lds[r][dd]);
                    pi[r] = fmaf(hv.x, wiv[0], pi[r]);
                    pi[r] = fmaf(hv.y, wiv[1], pi[r]);
                    pi[r] = fmaf(hv.z, wiv[2], pi[r]);
                    pi[r] = fmaf(hv.w, wiv[3], pi[r]);
                    pj[r] = fmaf(hv.x, wjv[0], pj[r]);
                    pj[r] = fmaf(hv.y, wjv[1], pj[r]);
                    pj[r] = fmaf(hv.z, wjv[2], pj[r]);
                    pj[r] = fmaf(hv.w, wjv[3], pj[r]);
                }
            }
#pragma unroll
            for (int r = 0; r < TIB; ++r) {
                scratch[g * 512 + r * 128 + o] = pi[r];
                scratch[2048 + g * 512 + r * 128 + o] = pj[r];
            }
        }
        __syncthreads();
        {
            const int rr = tid >> 7;
            const int o = tid & 127;
            float acci = b1n[o];
            float accj = 0.f;
#pragma unroll
            for (int g = 0; g < 4; ++g) {
                acci += scratch[g * 512 + rr * 128 + o];
                accj += scratch[2048 + g * 512 + rr * 128 + o];
            }
            ai_out[(size_t)(r0 + rr) * Dc + o] = acci;
            aj_out[(size_t)(r0 + rr) * Dc + o] = accj;
        }
    }
}

extern "C" void kernel_launch(void* const* d_in, const int* in_sizes, int n_in,
                              void* d_out, int out_size, void* d_ws, size_t ws_size,
                              hipStream_t stream) {
    const float* node = (const float*)d_in[0];
    const float* adj  = (const float*)d_in[1];
    const float* w1   = (const float*)d_in[2];
    const float* b1   = (const float*)d_in[3];
    const float* w2   = (const float*)d_in[4];
    const float* b2   = (const float*)d_in[5];
    float* out = (float*)d_out;

    float* ws = (float*)d_ws;
    float* wiT = ws; ws += Lc * Dc * Dc;
    float* wjT = ws; ws += Lc * Dc * Dc;
    float* w2T = ws; ws += Lc * Dc * Dc;
    float* ai  = ws; ws += BN * Dc;
    float* aj  = ws; ws += BN * Dc;
    float* ai2 = ws; ws += BN * Dc;
    float* aj2 = ws; ws += BN * Dc;
    float* h1  = ws; ws += BN * Dc;

    transpose_w_kernel<<<(Lc * Dc * Dc + 255) / 256, 256, 0, stream>>>(
        w1, w2, wiT, wjT, w2T);

    // layer 0: lin1, then fused msg+lin2+residual+lin1(layer1)
    gnn_lin1<<<BN / TN, 128, 0, stream>>>(node, wiT, wjT, b1, ai, aj);
    gnn_msgfull<true><<<BN / TIB, 512, 0, stream>>>(
        ai, aj, adj, node, w2T, b2, wiT + Dc * Dc, wjT + Dc * Dc, b1 + Dc,
        h1, ai2, aj2);
    // layer 1: fused msg+lin2+residual -> out
    gnn_msgfull<false><<<BN / TIB, 512, 0, stream>>>(
        ai2, aj2, adj, h1, w2T + Dc * Dc, b2 + Dc, nullptr, nullptr, nullptr,
        out, nullptr, nullptr);
}

// Round 13
// 55.025 us; speedup vs baseline: 1.0303x; 1.0008x over previous
//
#include <hip/hip_runtime.h>

// SimpleGNN: B=4, N=512, D=128, L=2 — round-9 verified best (50.7us), verbatim.
// msg[b,i,:] = (sum_j adj[b,i,j]*relu(ai'[b,i,:]+aj[b,j,:])) @ w2^T
//            + (sum_j adj[b,i,j]) * b2 ;  ai' = h@wi^T + b1, aj = h@wj^T
// 4 dispatches: transpose -> lin1 -> msgfull<true> -> msgfull<false>.
// msg stream iter = 1 float4 VMEM (2 j's) + 4 broadcast ds_read_b32 + 48 FMA.
// Weights read via transposed copies (coalesced); adj staged row-major [r][j].

constexpr int Bc = 4, Nc = 512, Dc = 128, Lc = 2;
constexpr int BN = Bc * Nc;  // 2048
constexpr int TIB = 4;       // rows per msgfull block
constexpr int TN = 4;        // rows per lin block

// --- weight transpose: wiT[l][d][o], wjT[l][d][o], w2T[l][d][o]
__global__ void transpose_w_kernel(const float* __restrict__ w1,
                                   const float* __restrict__ w2,
                                   float* __restrict__ wiT,
                                   float* __restrict__ wjT,
                                   float* __restrict__ w2T) {
    int idx = blockIdx.x * blockDim.x + threadIdx.x;
    if (idx >= Lc * Dc * Dc) return;
    int l = idx / (Dc * Dc);
    int rem = idx - l * Dc * Dc;
    int d = rem / Dc;
    int o = rem - d * Dc;
    wiT[idx] = w1[(l * Dc + o) * (2 * Dc) + d];
    wjT[idx] = w1[(l * Dc + o) * (2 * Dc) + Dc + d];
    w2T[idx] = w2[(l * Dc + o) * Dc + d];
}

// --- first linear (round-3 winner, verbatim)
__global__ __launch_bounds__(128) void gnn_lin1(const float* __restrict__ h,
                                                const float* __restrict__ wiT,
                                                const float* __restrict__ wjT,
                                                const float* __restrict__ b1,
                                                float* __restrict__ ai,
                                                float* __restrict__ aj) {
    __shared__ float hs[TN][Dc];
    const int o = threadIdx.x;
    const int r0 = blockIdx.x * TN;
#pragma unroll
    for (int t = 0; t < TN; ++t) hs[t][o] = h[(size_t)(r0 + t) * Dc + o];
    __syncthreads();
    float acci[TN], accj[TN];
    const float bo = b1[o];
#pragma unroll
    for (int t = 0; t < TN; ++t) { acci[t] = bo; accj[t] = 0.f; }
    for (int d = 0; d < Dc; d += 4) {
        float wi[4], wj[4];
#pragma unroll
        for (int k = 0; k < 4; ++k) {
            wi[k] = wiT[(size_t)(d + k) * Dc + o];
            wj[k] = wjT[(size_t)(d + k) * Dc + o];
        }
#pragma unroll
        for (int t = 0; t < TN; ++t) {
            const float4 hv = *reinterpret_cast<const float4*>(&hs[t][d]);
            acci[t] = fmaf(hv.x, wi[0], acci[t]);
            acci[t] = fmaf(hv.y, wi[1], acci[t]);
            acci[t] = fmaf(hv.z, wi[2], acci[t]);
            acci[t] = fmaf(hv.w, wi[3], acci[t]);
            accj[t] = fmaf(hv.x, wj[0], accj[t]);
            accj[t] = fmaf(hv.y, wj[1], accj[t]);
            accj[t] = fmaf(hv.z, wj[2], accj[t]);
            accj[t] = fmaf(hv.w, wj[3], accj[t]);
        }
    }
#pragma unroll
    for (int t = 0; t < TN; ++t) {
        ai[(size_t)(r0 + t) * Dc + o] = acci[t];
        aj[(size_t)(r0 + t) * Dc + o] = accj[t];
    }
}

// --- fused msg(v6) + lin2 + residual (+ lin1 of next layer).
// grid = BN/TIB = 512 blocks, 512 thr (8 waves). Wave w streams j in
// [w*64, w*64+64) as 32 float4 loads (2 j's each).
template <bool HAS_NEXT>
__global__ __launch_bounds__(512) void gnn_msgfull(
    const float* __restrict__ ai, const float* __restrict__ aj,
    const float* __restrict__ adj, const float* __restrict__ hin,
    const float* __restrict__ w2T, const float* __restrict__ b2,
    const float* __restrict__ wiT, const float* __restrict__ wjT,
    const float* __restrict__ b1, float* __restrict__ hout,
    float* __restrict__ ai_out, float* __restrict__ aj_out) {
    __shared__ __align__(16) float adjs[TIB][Nc];   // 8 KB  [r][j]
    __shared__ __align__(16) float scratch[4096];   // 16 KB (sred / GEMV partials)
    __shared__ float s_lds[TIB][Dc];                // 2 KB
    __shared__ float hnew_lds[TIB][Dc];             // 2 KB
    __shared__ float redw[8];

    const int tid = threadIdx.x;
    const int w = tid >> 6;
    const int lane = tid & 63;
    const int r0 = blockIdx.x * TIB;
    const int b = r0 >> 9;        // / Nc
    const int i0 = r0 & (Nc - 1);
    const float* __restrict__ ajb = aj + (size_t)b * Nc * Dc;
    const float* __restrict__ adjb = adj + (size_t)b * Nc * Nc;

    // ---- stage adjs [r][j] (coalesced) + arow wave partials
    {
        const int rr = tid >> 7;          // 0..3
        const int c4 = (tid & 127) * 4;
        const float4 av =
            *reinterpret_cast<const float4*>(&adjb[(size_t)(i0 + rr) * Nc + c4]);
        *reinterpret_cast<float4*>(&adjs[rr][c4]) = av;
        float p = av.x + av.y + av.z + av.w;
#pragma unroll
        for (int m = 32; m >= 1; m >>= 1) p += __shfl_xor(p, m);
        if (lane == 0) redw[w] = p;       // row (w>>1), col-half (w&1)
    }

    // ---- per-lane stream state: j-parity jlane, d-quad dq
    const int jlane = lane >> 5;          // 0/1
    const int dq = (lane & 31) * 4;       // 0..124
    float4 x[TIB], acc[TIB];
#pragma unroll
    for (int r = 0; r < TIB; ++r) {
        x[r] = *reinterpret_cast<const float4*>(&ai[(size_t)(r0 + r) * Dc + dq]);
        acc[r] = make_float4(0.f, 0.f, 0.f, 0.f);
    }
    __syncthreads();

    // ---- stream: 32 iters x (1 float4 VMEM + 4 LDS b32 + 48 VALU)
    const int jw = w * 64;
    const float* __restrict__ pbase = ajb + (size_t)(jw + jlane) * Dc + dq;
#pragma unroll 4
    for (int it = 0; it < 32; ++it) {
        const float4 v = *reinterpret_cast<const float4*>(pbase + (size_t)it * 256);
        const int j = jw + 2 * it + jlane;
        const float a0 = adjs[0][j];
        const float a1 = adjs[1][j];
        const float a2 = adjs[2][j];
        const float a3 = adjs[3][j];
#define ROWF(r, a)                                                       \
        acc[r].x = fmaf(a, fmaxf(x[r].x + v.x, 0.f), acc[r].x);          \
        acc[r].y = fmaf(a, fmaxf(x[r].y + v.y, 0.f), acc[r].y);          \
        acc[r].z = fmaf(a, fmaxf(x[r].z + v.z, 0.f), acc[r].z);          \
        acc[r].w = fmaf(a, fmaxf(x[r].w + v.w, 0.f), acc[r].w);
        ROWF(0, a0) ROWF(1, a1) ROWF(2, a2) ROWF(3, a3)
#undef ROWF
    }

    // ---- merge j-parity halves, park per-wave partials in scratch
#pragma unroll
    for (int r = 0; r < TIB; ++r) {
        acc[r].x += __shfl_xor(acc[r].x, 32);
        acc[r].y += __shfl_xor(acc[r].y, 32);
        acc[r].z += __shfl_xor(acc[r].z, 32);
        acc[r].w += __shfl_xor(acc[r].w, 32);
    }
    if (lane < 32) {
#pragma unroll
        for (int r = 0; r < TIB; ++r)
            *reinterpret_cast<float4*>(&scratch[w * 512 + r * 128 + dq]) = acc[r];
    }
    __syncthreads();

    // ---- reduce 8 wave-partials -> s_lds
    {
        const int rr = tid >> 7;
        const int dd = tid & 127;
        float s = 0.f;
#pragma unroll
        for (int ww = 0; ww < 8; ++ww) s += scratch[ww * 512 + rr * 128 + dd];
        s_lds[rr][dd] = s;
    }
    __syncthreads();

    // ---- lin2 GEMV, d-sliced: thread (o, g) does d in [g*32, g*32+32)
    {
        const int o = tid & 127;
        const int g = tid >> 7;
        float part[TIB] = {0.f, 0.f, 0.f, 0.f};
        for (int dd = g * 32; dd < g * 32 + 32; dd += 4) {
            float wv[4];
#pragma unroll
            for (int k = 0; k < 4; ++k) wv[k] = w2T[(size_t)(dd + k) * Dc + o];
#pragma unroll
            for (int r = 0; r < TIB; ++r) {
                const float4 sv = *reinterpret_cast<const float4*>(&s_lds[r][dd]);
                part[r] = fmaf(sv.x, wv[0], part[r]);
                part[r] = fmaf(sv.y, wv[1], part[r]);
                part[r] = fmaf(sv.z, wv[2], part[r]);
                part[r] = fmaf(sv.w, wv[3], part[r]);
            }
        }
#pragma unroll
        for (int r = 0; r < TIB; ++r) scratch[g * 512 + r * 128 + o] = part[r];
    }
    __syncthreads();

    // ---- combine partials + residual + b2*arow -> hnew
    {
        const int rr = tid >> 7;
        const int o = tid & 127;
        float a2c = scratch[rr * 128 + o] + scratch[512 + rr * 128 + o] +
                    scratch[1024 + rr * 128 + o] + scratch[1536 + rr * 128 + o];
        const float arow_r = redw[2 * rr] + redw[2 * rr + 1];
        const float hn =
            hin[(size_t)(r0 + rr) * Dc + o] + a2c + arow_r * b2[o];
        hout[(size_t)(r0 + rr) * Dc + o] = hn;
        if constexpr (HAS_NEXT) hnew_lds[rr][o] = hn;
    }

    if constexpr (HAS_NEXT) {
        __syncthreads();
        // ---- lin1 of next layer (wi and wj GEMVs), d-sliced
        {
            const int o = tid & 127;
            const int g = tid >> 7;
            float pi[TIB] = {0.f, 0.f, 0.f, 0.f};
            float pj[TIB] = {0.f, 0.f, 0.f, 0.f};
            for (int dd = g * 32; dd < g * 32 + 32; dd += 4) {
                float wiv[4], wjv[4];
#pragma unroll
                for (int k = 0; k < 4; ++k) {
                    wiv[k] = wiT[(size_t)(dd + k) * Dc + o];
                    wjv[k] = wjT[(size_t)(dd + k) * Dc + o];
                }
#pragma unroll
                for (int r = 0; r < TIB; ++r) {
                    const float4 hv =
                        *reinterpret_cast<const float4*>(&hnew_lds[r][dd]);
                    pi[r] = fmaf(hv.x, wiv[0], pi[r]);
                    pi[r] = fmaf(hv.y, wiv[1], pi[r]);
                    pi[r] = fmaf(hv.z, wiv[2], pi[r]);
                    pi[r] = fmaf(hv.w, wiv[3], pi[r]);
                    pj[r] = fmaf(hv.x, wjv[0], pj[r]);
                    pj[r] = fmaf(hv.y, wjv[1], pj[r]);
                    pj[r] = fmaf(hv.z, wjv[2], pj[r]);
                    pj[r] = fmaf(hv.w, wjv[3], pj[r]);
                }
            }
#pragma unroll
            for (int r = 0; r < TIB; ++r) {
                scratch[g * 512 + r * 128 + o] = pi[r];
                scratch[2048 + g * 512 + r * 128 + o] = pj[r];
            }
        }
        __syncthreads();
        {
            const int rr = tid >> 7;
            const int o = tid & 127;
            float acci = b1[o];
            float accj = 0.f;
#pragma unroll
            for (int g = 0; g < 4; ++g) {
                acci += scratch[g * 512 + rr * 128 + o];
                accj += scratch[2048 + g * 512 + rr * 128 + o];
            }
            ai_out[(size_t)(r0 + rr) * Dc + o] = acci;
            aj_out[(size_t)(r0 + rr) * Dc + o] = accj;
        }
    }
}

extern "C" void kernel_launch(void* const* d_in, const int* in_sizes, int n_in,
                              void* d_out, int out_size, void* d_ws, size_t ws_size,
                              hipStream_t stream) {
    const float* node = (const float*)d_in[0];
    const float* adj  = (const float*)d_in[1];
    const float* w1   = (const float*)d_in[2];
    const float* b1   = (const float*)d_in[3];
    const float* w2   = (const float*)d_in[4];
    const float* b2   = (const float*)d_in[5];
    float* out = (float*)d_out;

    float* ws = (float*)d_ws;
    float* wiT = ws; ws += Lc * Dc * Dc;
    float* wjT = ws; ws += Lc * Dc * Dc;
    float* w2T = ws; ws += Lc * Dc * Dc;
    float* ai  = ws; ws += BN * Dc;
    float* aj  = ws; ws += BN * Dc;
    float* ai2 = ws; ws += BN * Dc;
    float* aj2 = ws; ws += BN * Dc;
    float* h1  = ws; ws += BN * Dc;

    transpose_w_kernel<<<(Lc * Dc * Dc + 255) / 256, 256, 0, stream>>>(
        w1, w2, wiT, wjT, w2T);

    // layer 0: lin1, then fused msg+lin2+residual+lin1(layer1)
    gnn_lin1<<<BN / TN, 128, 0, stream>>>(node, wiT, wjT, b1, ai, aj);
    gnn_msgfull<true><<<BN / TIB, 512, 0, stream>>>(
        ai, aj, adj, node, w2T, b2, wiT + Dc * Dc, wjT + Dc * Dc, b1 + Dc,
        h1, ai2, aj2);
    // layer 1: fused msg+lin2+residual -> out
    gnn_msgfull<false><<<BN / TIB, 512, 0, stream>>>(
        ai2, aj2, adj, h1, w2T + Dc * Dc, b2 + Dc, nullptr, nullptr, nullptr,
        out, nullptr, nullptr);
}

// Round 14
// 54.752 us; speedup vs baseline: 1.0354x; 1.0050x over previous
//
#include <hip/hip_runtime.h>
#include <hip/hip_cooperative_groups.h>

namespace cg = cooperative_groups;

// SimpleGNN: B=4, N=512, D=128, L=2.
// msg[b,i,:] = (sum_j adj[b,i,j]*relu(ai'[b,i,:]+aj[b,j,:])) @ w2^T
//            + (sum_j adj[b,i,j]) * b2 ;  ai' = h@wi^T + b1, aj = h@wj^T
// Primary: ONE cooperative dispatch (512 blocks x 256 thr, 2 blocks/CU gated
// by an occupancy query; launch return checked). Fallback: the verified
// 4-dispatch round-9/13 pipeline, byte-identical.

constexpr int Bc = 4, Nc = 512, Dc = 128, Lc = 2;
constexpr int BN = Bc * Nc;   // 2048
constexpr int TIB = 4;        // rows per block
constexpr int TN = 4;         // rows per lin block (fallback)
constexpr int CTHR = 256;     // coop block size (4 waves)
constexpr int CBLK = BN / TIB;// 512 blocks

// ======================= cooperative all-in-one ==============================
struct SMC {
    float adjs[TIB][Nc];     // 8 KB [r][j]
    float scratch[4096];     // 16 KB
    float s_lds[TIB][Dc];    // 2 KB
    float hnew[TIB][Dc];     // 2 KB
    float redw[TIB];         // arow per row
};

// lin1 GEMV on sm.hnew (4 rows), d-sliced in halves. Caller must have synced
// after writing hnew. Writes ai_out/aj_out for rows r0..r0+3.
__device__ __forceinline__ void lin1_lds_256(SMC& sm, int tid, int r0,
                                             const float* __restrict__ wiT_l,
                                             const float* __restrict__ wjT_l,
                                             const float* __restrict__ b1_l,
                                             float* __restrict__ ai_out,
                                             float* __restrict__ aj_out) {
    {
        const int o = tid & 127;
        const int g = tid >> 7;  // 0/1 -> d in [g*64, g*64+64)
        float pi[TIB] = {0.f, 0.f, 0.f, 0.f};
        float pj[TIB] = {0.f, 0.f, 0.f, 0.f};
        for (int dd = g * 64; dd < g * 64 + 64; dd += 4) {
            float wiv[4], wjv[4];
#pragma unroll
            for (int k = 0; k < 4; ++k) {
                wiv[k] = wiT_l[(size_t)(dd + k) * Dc + o];
                wjv[k] = wjT_l[(size_t)(dd + k) * Dc + o];
            }
#pragma unroll
            for (int r = 0; r < TIB; ++r) {
                const float4 hv = *reinterpret_cast<const float4*>(&sm.hnew[r][dd]);
                pi[r] = fmaf(hv.x, wiv[0], pi[r]);
                pi[r] = fmaf(hv.y, wiv[1], pi[r]);
                pi[r] = fmaf(hv.z, wiv[2], pi[r]);
                pi[r] = fmaf(hv.w, wiv[3], pi[r]);
                pj[r] = fmaf(hv.x, wjv[0], pj[r]);
                pj[r] = fmaf(hv.y, wjv[1], pj[r]);
                pj[r] = fmaf(hv.z, wjv[2], pj[r]);
                pj[r] = fmaf(hv.w, wjv[3], pj[r]);
            }
        }
#pragma unroll
        for (int r = 0; r < TIB; ++r) {
            sm.scratch[g * 512 + r * 128 + o] = pi[r];
            sm.scratch[2048 + g * 512 + r * 128 + o] = pj[r];
        }
    }
    __syncthreads();
#pragma unroll
    for (int rep = 0; rep < 2; ++rep) {
        const int lin = rep * 256 + tid;
        const int rr = lin >> 7;
        const int oo = lin & 127;
        const float acci = b1_l[oo] + sm.scratch[rr * 128 + oo] +
                           sm.scratch[512 + rr * 128 + oo];
        const float accj = sm.scratch[2048 + rr * 128 + oo] +
                           sm.scratch[2048 + 512 + rr * 128 + oo];
        ai_out[(size_t)(r0 + rr) * Dc + oo] = acci;
        aj_out[(size_t)(r0 + rr) * Dc + oo] = accj;
    }
}

// msg + lin2 + residual. 4 waves; wave w streams j in [w*128,(w+1)*128) as
// 64 float4 iters (2 j's each). Ends synced-after-combine only if caller syncs.
__device__ __forceinline__ void msg_phase_256(
    SMC& sm, int tid, int r0, int b, int i0, const float* __restrict__ ai_in,
    const float* __restrict__ aj_in, const float* __restrict__ adj,
    const float* __restrict__ hin, const float* __restrict__ w2T_l,
    const float* __restrict__ b2_l, float* __restrict__ hout, bool toLds) {
    const int w = tid >> 6;
    const int lane = tid & 63;
    const float* __restrict__ ajb = aj_in + (size_t)b * Nc * Dc;
    const float* __restrict__ adjb = adj + (size_t)b * Nc * Nc;

    // ---- stage adjs: wave w loads row w (64 lanes x 8 floats, coalesced)
    {
        const int c8 = lane * 8;
        const float4 a4 = *reinterpret_cast<const float4*>(
            &adjb[(size_t)(i0 + w) * Nc + c8]);
        const float4 b4 = *reinterpret_cast<const float4*>(
            &adjb[(size_t)(i0 + w) * Nc + c8 + 4]);
        *reinterpret_cast<float4*>(&sm.adjs[w][c8]) = a4;
        *reinterpret_cast<float4*>(&sm.adjs[w][c8 + 4]) = b4;
        float p = a4.x + a4.y + a4.z + a4.w + b4.x + b4.y + b4.z + b4.w;
#pragma unroll
        for (int m = 32; m >= 1; m >>= 1) p += __shfl_xor(p, m);
        if (lane == 0) sm.redw[w] = p;
    }

    // ---- per-lane stream state
    const int jlane = lane >> 5;       // 0/1
    const int dq = (lane & 31) * 4;    // 0..124
    float4 x[TIB], acc[TIB];
#pragma unroll
    for (int r = 0; r < TIB; ++r) {
        x[r] = *reinterpret_cast<const float4*>(&ai_in[(size_t)(r0 + r) * Dc + dq]);
        acc[r] = make_float4(0.f, 0.f, 0.f, 0.f);
    }
    __syncthreads();

    // ---- stream: 64 iters x (1 float4 VMEM + 4 LDS b32 + 48 VALU)
    const int jw = w * 128;
    const float* __restrict__ pbase = ajb + (size_t)(jw + jlane) * Dc + dq;
#pragma unroll 4
    for (int it = 0; it < 64; ++it) {
        const float4 v = *reinterpret_cast<const float4*>(pbase + (size_t)it * 256);
        const int j = jw + 2 * it + jlane;
        const float a0 = sm.adjs[0][j];
        const float a1 = sm.adjs[1][j];
        const float a2 = sm.adjs[2][j];
        const float a3 = sm.adjs[3][j];
#define ROWF(r, a)                                                       \
        acc[r].x = fmaf(a, fmaxf(x[r].x + v.x, 0.f), acc[r].x);          \
        acc[r].y = fmaf(a, fmaxf(x[r].y + v.y, 0.f), acc[r].y);          \
        acc[r].z = fmaf(a, fmaxf(x[r].z + v.z, 0.f), acc[r].z);          \
        acc[r].w = fmaf(a, fmaxf(x[r].w + v.w, 0.f), acc[r].w);
        ROWF(0, a0) ROWF(1, a1) ROWF(2, a2) ROWF(3, a3)
#undef ROWF
    }

    // ---- merge j-parity halves, park per-wave partials
#pragma unroll
    for (int r = 0; r < TIB; ++r) {
        acc[r].x += __shfl_xor(acc[r].x, 32);
        acc[r].y += __shfl_xor(acc[r].y, 32);
        acc[r].z += __shfl_xor(acc[r].z, 32);
        acc[r].w += __shfl_xor(acc[r].w, 32);
    }
    if (lane < 32) {
#pragma unroll
        for (int r = 0; r < TIB; ++r)
            *reinterpret_cast<float4*>(&sm.scratch[w * 512 + r * 128 + dq]) =
                acc[r];
    }
    __syncthreads();

    // ---- reduce 4 wave partials -> s_lds
#pragma unroll
    for (int rep = 0; rep < 2; ++rep) {
        const int lin = rep * 256 + tid;
        const int rr = lin >> 7;
        const int dd = lin & 127;
        sm.s_lds[rr][dd] = sm.scratch[rr * 128 + dd] +
                           sm.scratch[512 + rr * 128 + dd] +
                           sm.scratch[1024 + rr * 128 + dd] +
                           sm.scratch[1536 + rr * 128 + dd];
    }
    __syncthreads();

    // ---- lin2 GEMV, d-sliced halves
    {
        const int o = tid & 127;
        const int g = tid >> 7;
        float part[TIB] = {0.f, 0.f, 0.f, 0.f};
        for (int dd = g * 64; dd < g * 64 + 64; dd += 4) {
            float wv[4];
#pragma unroll
            for (int k = 0; k < 4; ++k) wv[k] = w2T_l[(size_t)(dd + k) * Dc + o];
#pragma unroll
            for (int r = 0; r < TIB; ++r) {
                const float4 sv = *reinterpret_cast<const float4*>(&sm.s_lds[r][dd]);
                part[r] = fmaf(sv.x, wv[0], part[r]);
                part[r] = fmaf(sv.y, wv[1], part[r]);
                part[r] = fmaf(sv.z, wv[2], part[r]);
                part[r] = fmaf(sv.w, wv[3], part[r]);
            }
        }
#pragma unroll
        for (int r = 0; r < TIB; ++r) sm.scratch[g * 512 + r * 128 + o] = part[r];
    }
    __syncthreads();

    // ---- combine + residual + b2*arow -> hout (+hnew)
#pragma unroll
    for (int rep = 0; rep < 2; ++rep) {
        const int lin = rep * 256 + tid;
        const int rr = lin >> 7;
        const int oo = lin & 127;
        const float a2c =
            sm.scratch[rr * 128 + oo] + sm.scratch[512 + rr * 128 + oo];
        const float hn = hin[(size_t)(r0 + rr) * Dc + oo] + a2c +
                         sm.redw[rr] * b2_l[oo];
        hout[(size_t)(r0 + rr) * Dc + oo] = hn;
        if (toLds) sm.hnew[rr][oo] = hn;
    }
}

__global__ __launch_bounds__(CTHR) void gnn_all(
    const float* __restrict__ node, const float* __restrict__ adj,
    const float* __restrict__ w1, const float* __restrict__ b1,
    const float* __restrict__ w2, const float* __restrict__ b2,
    float* __restrict__ out, float* __restrict__ wiT, float* __restrict__ wjT,
    float* __restrict__ w2T, float* __restrict__ ai, float* __restrict__ aj,
    float* __restrict__ ai2, float* __restrict__ aj2, float* __restrict__ h1) {
    cg::grid_group grid = cg::this_grid();
    __shared__ SMC sm;
    const int tid = threadIdx.x;
    const int blk = blockIdx.x;
    const int r0 = blk * TIB;
    const int b = r0 >> 9;        // / Nc
    const int i0 = r0 & (Nc - 1);

    // ---- phase 0: weight transpose
    {
        const int idx = blk * CTHR + tid;
        if (idx < Lc * Dc * Dc) {
            const int l = idx >> 14;
            const int rem = idx & (Dc * Dc - 1);
            const int d = rem >> 7;
            const int o = rem & 127;
            wiT[idx] = w1[(size_t)(l * Dc + o) * (2 * Dc) + d];
            wjT[idx] = w1[(size_t)(l * Dc + o) * (2 * Dc) + Dc + d];
            w2T[idx] = w2[(size_t)(l * Dc + o) * Dc + d];
        }
    }
    grid.sync();

    // ---- phase 1: lin1 of layer 0
#pragma unroll
    for (int rep = 0; rep < 2; ++rep) {
        const int lin = rep * 256 + tid;
        sm.hnew[lin >> 7][lin & 127] =
            node[(size_t)(r0 + (lin >> 7)) * Dc + (lin & 127)];
    }
    __syncthreads();
    lin1_lds_256(sm, tid, r0, wiT, wjT, b1, ai, aj);
    grid.sync();

    // ---- phase 2: L0 msg + lin2 + residual, then lin1 of L1
    msg_phase_256(sm, tid, r0, b, i0, ai, aj, adj, node, w2T, b2, h1, true);
    __syncthreads();
    lin1_lds_256(sm, tid, r0, wiT + Dc * Dc, wjT + Dc * Dc, b1 + Dc, ai2, aj2);
    grid.sync();

    // ---- phase 3: L1 msg + lin2 + residual -> out
    msg_phase_256(sm, tid, r0, b, i0, ai2, aj2, adj, h1, w2T + Dc * Dc, b2 + Dc,
                  out, false);
}

// ======================= fallback: round-9/13 pipeline =======================
__global__ void transpose_w_kernel(const float* __restrict__ w1,
                                   const float* __restrict__ w2,
                                   float* __restrict__ wiT,
                                   float* __restrict__ wjT,
                                   float* __restrict__ w2T) {
    int idx = blockIdx.x * blockDim.x + threadIdx.x;
    if (idx >= Lc * Dc * Dc) return;
    int l = idx / (Dc * Dc);
    int rem = idx - l * Dc * Dc;
    int d = rem / Dc;
    int o = rem - d * Dc;
    wiT[idx] = w1[(l * Dc + o) * (2 * Dc) + d];
    wjT[idx] = w1[(l * Dc + o) * (2 * Dc) + Dc + d];
    w2T[idx] = w2[(l * Dc + o) * Dc + d];
}

__global__ __launch_bounds__(128) void gnn_lin1(const float* __restrict__ h,
                                                const float* __restrict__ wiT,
                                                const float* __restrict__ wjT,
                                                const float* __restrict__ b1,
                                                float* __restrict__ ai,
                                                float* __restrict__ aj) {
    __shared__ float hs[TN][Dc];
    const int o = threadIdx.x;
    const int r0 = blockIdx.x * TN;
#pragma unroll
    for (int t = 0; t < TN; ++t) hs[t][o] = h[(size_t)(r0 + t) * Dc + o];
    __syncthreads();
    float acci[TN], accj[TN];
    const float bo = b1[o];
#pragma unroll
    for (int t = 0; t < TN; ++t) { acci[t] = bo; accj[t] = 0.f; }
    for (int d = 0; d < Dc; d += 4) {
        float wi[4], wj[4];
#pragma unroll
        for (int k = 0; k < 4; ++k) {
            wi[k] = wiT[(size_t)(d + k) * Dc + o];
            wj[k] = wjT[(size_t)(d + k) * Dc + o];
        }
#pragma unroll
        for (int t = 0; t < TN; ++t) {
            const float4 hv = *reinterpret_cast<const float4*>(&hs[t][d]);
            acci[t] = fmaf(hv.x, wi[0], acci[t]);
            acci[t] = fmaf(hv.y, wi[1], acci[t]);
            acci[t] = fmaf(hv.z, wi[2], acci[t]);
            acci[t] = fmaf(hv.w, wi[3], acci[t]);
            accj[t] = fmaf(hv.x, wj[0], accj[t]);
            accj[t] = fmaf(hv.y, wj[1], accj[t]);
            accj[t] = fmaf(hv.z, wj[2], accj[t]);
            accj[t] = fmaf(hv.w, wj[3], accj[t]);
        }
    }
#pragma unroll
    for (int t = 0; t < TN; ++t) {
        ai[(size_t)(r0 + t) * Dc + o] = acci[t];
        aj[(size_t)(r0 + t) * Dc + o] = accj[t];
    }
}

template <bool HAS_NEXT>
__global__ __launch_bounds__(512) void gnn_msgfull(
    const float* __restrict__ ai, const float* __restrict__ aj,
    const float* __restrict__ adj, const float* __restrict__ hin,
    const float* __restrict__ w2T, const float* __restrict__ b2,
    const float* __restrict__ wiT, const float* __restrict__ wjT,
    const float* __restrict__ b1, float* __restrict__ hout,
    float* __restrict__ ai_out, float* __restrict__ aj_out) {
    __shared__ __align__(16) float adjs[TIB][Nc];
    __shared__ __align__(16) float scratch[4096];
    __shared__ float s_lds[TIB][Dc];
    __shared__ float hnew_lds[TIB][Dc];
    __shared__ float redw[8];

    const int tid = threadIdx.x;
    const int w = tid >> 6;
    const int lane = tid & 63;
    const int r0 = blockIdx.x * TIB;
    const int b = r0 >> 9;
    const int i0 = r0 & (Nc - 1);
    const float* __restrict__ ajb = aj + (size_t)b * Nc * Dc;
    const float* __restrict__ adjb = adj + (size_t)b * Nc * Nc;

    {
        const int rr = tid >> 7;
        const int c4 = (tid & 127) * 4;
        const float4 av =
            *reinterpret_cast<const float4*>(&adjb[(size_t)(i0 + rr) * Nc + c4]);
        *reinterpret_cast<float4*>(&adjs[rr][c4]) = av;
        float p = av.x + av.y + av.z + av.w;
#pragma unroll
        for (int m = 32; m >= 1; m >>= 1) p += __shfl_xor(p, m);
        if (lane == 0) redw[w] = p;
    }

    const int jlane = lane >> 5;
    const int dq = (lane & 31) * 4;
    float4 x[TIB], acc[TIB];
#pragma unroll
    for (int r = 0; r < TIB; ++r) {
        x[r] = *reinterpret_cast<const float4*>(&ai[(size_t)(r0 + r) * Dc + dq]);
        acc[r] = make_float4(0.f, 0.f, 0.f, 0.f);
    }
    __syncthreads();

    const int jw = w * 64;
    const float* __restrict__ pbase = ajb + (size_t)(jw + jlane) * Dc + dq;
#pragma unroll 4
    for (int it = 0; it < 32; ++it) {
        const float4 v = *reinterpret_cast<const float4*>(pbase + (size_t)it * 256);
        const int j = jw + 2 * it + jlane;
        const float a0 = adjs[0][j];
        const float a1 = adjs[1][j];
        const float a2 = adjs[2][j];
        const float a3 = adjs[3][j];
#define ROWF(r, a)                                                       \
        acc[r].x = fmaf(a, fmaxf(x[r].x + v.x, 0.f), acc[r].x);          \
        acc[r].y = fmaf(a, fmaxf(x[r].y + v.y, 0.f), acc[r].y);          \
        acc[r].z = fmaf(a, fmaxf(x[r].z + v.z, 0.f), acc[r].z);          \
        acc[r].w = fmaf(a, fmaxf(x[r].w + v.w, 0.f), acc[r].w);
        ROWF(0, a0) ROWF(1, a1) ROWF(2, a2) ROWF(3, a3)
#undef ROWF
    }

#pragma unroll
    for (int r = 0; r < TIB; ++r) {
        acc[r].x += __shfl_xor(acc[r].x, 32);
        acc[r].y += __shfl_xor(acc[r].y, 32);
        acc[r].z += __shfl_xor(acc[r].z, 32);
        acc[r].w += __shfl_xor(acc[r].w, 32);
    }
    if (lane < 32) {
#pragma unroll
        for (int r = 0; r < TIB; ++r)
            *reinterpret_cast<float4*>(&scratch[w * 512 + r * 128 + dq]) = acc[r];
    }
    __syncthreads();

    {
        const int rr = tid >> 7;
        const int dd = tid & 127;
        float s = 0.f;
#pragma unroll
        for (int ww = 0; ww < 8; ++ww) s += scratch[ww * 512 + rr * 128 + dd];
        s_lds[rr][dd] = s;
    }
    __syncthreads();

    {
        const int o = tid & 127;
        const int g = tid >> 7;
        float part[TIB] = {0.f, 0.f, 0.f, 0.f};
        for (int dd = g * 32; dd < g * 32 + 32; dd += 4) {
            float wv[4];
#pragma unroll
            for (int k = 0; k < 4; ++k) wv[k] = w2T[(size_t)(dd + k) * Dc + o];
#pragma unroll
            for (int r = 0; r < TIB; ++r) {
                const float4 sv = *reinterpret_cast<const float4*>(&s_lds[r][dd]);
                part[r] = fmaf(sv.x, wv[0], part[r]);
                part[r] = fmaf(sv.y, wv[1], part[r]);
                part[r] = fmaf(sv.z, wv[2], part[r]);
                part[r] = fmaf(sv.w, wv[3], part[r]);
            }
        }
#pragma unroll
        for (int r = 0; r < TIB; ++r) scratch[g * 512 + r * 128 + o] = part[r];
    }
    __syncthreads();

    {
        const int rr = tid >> 7;
        const int o = tid & 127;
        float a2c = scratch[rr * 128 + o] + scratch[512 + rr * 128 + o] +
                    scratch[1024 + rr * 128 + o] + scratch[1536 + rr * 128 + o];
        const float arow_r = redw[2 * rr] + redw[2 * rr + 1];
        const float hn = hin[(size_t)(r0 + rr) * Dc + o] + a2c + arow_r * b2[o];
        hout[(size_t)(r0 + rr) * Dc + o] = hn;
        if constexpr (HAS_NEXT) hnew_lds[rr][o] = hn;
    }

    if constexpr (HAS_NEXT) {
        __syncthreads();
        {
            const int o = tid & 127;
            const int g = tid >> 7;
            float pi[TIB] = {0.f, 0.f, 0.f, 0.f};
            float pj[TIB] = {0.f, 0.f, 0.f, 0.f};
            for (int dd = g * 32; dd < g * 32 + 32; dd += 4) {
                float wiv[4], wjv[4];
#pragma unroll
                for (int k = 0; k < 4; ++k) {
                    wiv[k] = wiT[(size_t)(dd + k) * Dc + o];
                    wjv[k] = wjT[(size_t)(dd + k) * Dc + o];
                }
#pragma unroll
                for (int r = 0; r < TIB; ++r) {
                    const float4 hv =
                        *reinterpret_cast<const float4*>(&hnew_lds[r][dd]);
                    pi[r] = fmaf(hv.x, wiv[0], pi[r]);
                    pi[r] = fmaf(hv.y, wiv[1], pi[r]);
                    pi[r] = fmaf(hv.z, wiv[2], pi[r]);
                    pi[r] = fmaf(hv.w, wiv[3], pi[r]);
                    pj[r] = fmaf(hv.x, wjv[0], pj[r]);
                    pj[r] = fmaf(hv.y, wjv[1], pj[r]);
                    pj[r] = fmaf(hv.z, wjv[2], pj[r]);
                    pj[r] = fmaf(hv.w, wjv[3], pj[r]);
                }
            }
#pragma unroll
            for (int r = 0; r < TIB; ++r) {
                scratch[g * 512 + r * 128 + o] = pi[r];
                scratch[2048 + g * 512 + r * 128 + o] = pj[r];
            }
        }
        __syncthreads();
        {
            const int rr = tid >> 7;
            const int o = tid & 127;
            float acci = b1[o];
            float accj = 0.f;
#pragma unroll
            for (int g = 0; g < 4; ++g) {
                acci += scratch[g * 512 + rr * 128 + o];
                accj += scratch[2048 + g * 512 + rr * 128 + o];
            }
            ai_out[(size_t)(r0 + rr) * Dc + o] = acci;
            aj_out[(size_t)(r0 + rr) * Dc + o] = accj;
        }
    }
}

extern "C" void kernel_launch(void* const* d_in, const int* in_sizes, int n_in,
                              void* d_out, int out_size, void* d_ws, size_t ws_size,
                              hipStream_t stream) {
    const float* node = (const float*)d_in[0];
    const float* adj  = (const float*)d_in[1];
    const float* w1   = (const float*)d_in[2];
    const float* b1   = (const float*)d_in[3];
    const float* w2   = (const float*)d_in[4];
    const float* b2   = (const float*)d_in[5];
    float* out = (float*)d_out;

    float* ws = (float*)d_ws;
    float* wiT = ws; ws += Lc * Dc * Dc;
    float* wjT = ws; ws += Lc * Dc * Dc;
    float* w2T = ws; ws += Lc * Dc * Dc;
    float* ai  = ws; ws += BN * Dc;
    float* aj  = ws; ws += BN * Dc;
    float* ai2 = ws; ws += BN * Dc;
    float* aj2 = ws; ws += BN * Dc;
    float* h1  = ws; ws += BN * Dc;

    // ---- gate: coop requires >= 2 co-resident blocks/CU (512 blocks total)
    int maxBlk = 0;
    hipError_t qe =
        hipOccupancyMaxActiveBlocksPerMultiprocessor(&maxBlk, gnn_all, CTHR, 0);
    bool coop = (qe == hipSuccess) && (maxBlk >= 2);

    if (coop) {
        void* kargs[] = {(void*)&node, (void*)&adj, (void*)&w1,  (void*)&b1,
                         (void*)&w2,   (void*)&b2,  (void*)&out, (void*)&wiT,
                         (void*)&wjT,  (void*)&w2T, (void*)&ai,  (void*)&aj,
                         (void*)&ai2,  (void*)&aj2, (void*)&h1};
        hipError_t le = hipLaunchCooperativeKernel(
            (const void*)gnn_all, dim3(CBLK), dim3(CTHR), kargs, 0, stream);
        if (le != hipSuccess) {
            (void)hipGetLastError();  // clear sticky error, fall back
            coop = false;
        }
    }

    if (!coop) {
        transpose_w_kernel<<<(Lc * Dc * Dc + 255) / 256, 256, 0, stream>>>(
            w1, w2, wiT, wjT, w2T);
        gnn_lin1<<<BN / TN, 128, 0, stream>>>(node, wiT, wjT, b1, ai, aj);
        gnn_msgfull<true><<<BN / TIB, 512, 0, stream>>>(
            ai, aj, adj, node, w2T, b2, wiT + Dc * Dc, wjT + Dc * Dc, b1 + Dc,
            h1, ai2, aj2);
        gnn_msgfull<false><<<BN / TIB, 512, 0, stream>>>(
            ai2, aj2, adj, h1, w2T + Dc * Dc, b2 + Dc, nullptr, nullptr,
            nullptr, out, nullptr, nullptr);
    }
}

// Round 15
// 48.233 us; speedup vs baseline: 1.1753x; 1.1352x over previous
//
#include <hip/hip_runtime.h>

// SimpleGNN: B=4, N=512, D=128, L=2 — 3 dispatches.
// msg[b,i,:] = (sum_j adj[b,i,j]*relu(ai'[b,i,:]+aj[b,j,:])) @ w2^T
//            + (sum_j adj[b,i,j]) * b2 ;  ai' = h@wi^T + b1, aj = h@wj^T
// Round-9 verified structure, minus one dispatch: the weight transpose rides
// as 64 extra blocks inside the lin1 dispatch (lin1 reads w1 in natural
// layout, so it doesn't depend on the transposed copies; msgfull does, and
// stream order guarantees they're ready). Coop single-dispatch is dead here:
// hipLaunchCooperativeKernel fails under the harness's graph capture (r14).

constexpr int Bc = 4, Nc = 512, Dc = 128, Lc = 2;
constexpr int BN = Bc * Nc;  // 2048
constexpr int TIB = 4;       // rows per msgfull block
constexpr int TN = 4;        // rows per lin block
constexpr int TBLK = 64;     // transpose rider blocks (128 thr each)

// --- combined: blocks [0,512) = lin1 layer 0 (natural w1 reads);
//               blocks [512,576) = transpose wiT/wjT/w2T for later dispatches.
__global__ __launch_bounds__(128) void gnn_lin1_trans(
    const float* __restrict__ node, const float* __restrict__ w1,
    const float* __restrict__ b1, const float* __restrict__ w2,
    float* __restrict__ ai, float* __restrict__ aj, float* __restrict__ wiT,
    float* __restrict__ wjT, float* __restrict__ w2T) {
    const int blk = blockIdx.x;
    if (blk < BN / TN) {
        // ---- lin1, natural-layout weights (thread o streams w1 row o)
        __shared__ float hs[TN][Dc];
        const int o = threadIdx.x;
        const int r0 = blk * TN;
#pragma unroll
        for (int t = 0; t < TN; ++t) hs[t][o] = node[(size_t)(r0 + t) * Dc + o];
        __syncthreads();
        float acci[TN], accj[TN];
        const float bo = b1[o];
#pragma unroll
        for (int t = 0; t < TN; ++t) { acci[t] = bo; accj[t] = 0.f; }
        const float* __restrict__ w1row = w1 + (size_t)o * (2 * Dc);
        for (int d = 0; d < Dc; d += 4) {
            const float4 wi = *reinterpret_cast<const float4*>(&w1row[d]);
            const float4 wj = *reinterpret_cast<const float4*>(&w1row[Dc + d]);
#pragma unroll
            for (int t = 0; t < TN; ++t) {
                const float4 hv = *reinterpret_cast<const float4*>(&hs[t][d]);
                acci[t] = fmaf(hv.x, wi.x, acci[t]);
                acci[t] = fmaf(hv.y, wi.y, acci[t]);
                acci[t] = fmaf(hv.z, wi.z, acci[t]);
                acci[t] = fmaf(hv.w, wi.w, acci[t]);
                accj[t] = fmaf(hv.x, wj.x, accj[t]);
                accj[t] = fmaf(hv.y, wj.y, accj[t]);
                accj[t] = fmaf(hv.z, wj.z, accj[t]);
                accj[t] = fmaf(hv.w, wj.w, accj[t]);
            }
        }
#pragma unroll
        for (int t = 0; t < TN; ++t) {
            ai[(size_t)(r0 + t) * Dc + o] = acci[t];
            aj[(size_t)(r0 + t) * Dc + o] = accj[t];
        }
    } else {
        // ---- transpose rider: wiT/wjT/w2T [l][d][o] <- w1/w2 [l][o][*]
        const int base = (blk - BN / TN) * 128 + threadIdx.x;  // 0..8191
        for (int idx = base; idx < Lc * Dc * Dc; idx += TBLK * 128) {
            const int l = idx >> 14;
            const int rem = idx & (Dc * Dc - 1);
            const int d = rem >> 7;
            const int o = rem & 127;
            wiT[idx] = w1[(size_t)(l * Dc + o) * (2 * Dc) + d];
            wjT[idx] = w1[(size_t)(l * Dc + o) * (2 * Dc) + Dc + d];
            w2T[idx] = w2[(size_t)(l * Dc + o) * Dc + d];
        }
    }
}

// --- fused msg + lin2 + residual (+ lin1 of next layer) — round-9 verbatim.
// grid = BN/TIB = 512 blocks, 512 thr (8 waves). Wave w streams j in
// [w*64, w*64+64) as 32 float4 loads (2 j's each).
template <bool HAS_NEXT>
__global__ __launch_bounds__(512) void gnn_msgfull(
    const float* __restrict__ ai, const float* __restrict__ aj,
    const float* __restrict__ adj, const float* __restrict__ hin,
    const float* __restrict__ w2T, const float* __restrict__ b2,
    const float* __restrict__ wiT, const float* __restrict__ wjT,
    const float* __restrict__ b1, float* __restrict__ hout,
    float* __restrict__ ai_out, float* __restrict__ aj_out) {
    __shared__ __align__(16) float adjs[TIB][Nc];   // 8 KB  [r][j]
    __shared__ __align__(16) float scratch[4096];   // 16 KB
    __shared__ float s_lds[TIB][Dc];                // 2 KB
    __shared__ float hnew_lds[TIB][Dc];             // 2 KB
    __shared__ float redw[8];

    const int tid = threadIdx.x;
    const int w = tid >> 6;
    const int lane = tid & 63;
    const int r0 = blockIdx.x * TIB;
    const int b = r0 >> 9;        // / Nc
    const int i0 = r0 & (Nc - 1);
    const float* __restrict__ ajb = aj + (size_t)b * Nc * Dc;
    const float* __restrict__ adjb = adj + (size_t)b * Nc * Nc;

    // ---- stage adjs [r][j] (coalesced) + arow wave partials
    {
        const int rr = tid >> 7;          // 0..3
        const int c4 = (tid & 127) * 4;
        const float4 av =
            *reinterpret_cast<const float4*>(&adjb[(size_t)(i0 + rr) * Nc + c4]);
        *reinterpret_cast<float4*>(&adjs[rr][c4]) = av;
        float p = av.x + av.y + av.z + av.w;
#pragma unroll
        for (int m = 32; m >= 1; m >>= 1) p += __shfl_xor(p, m);
        if (lane == 0) redw[w] = p;       // row (w>>1), col-half (w&1)
    }

    // ---- per-lane stream state: j-parity jlane, d-quad dq
    const int jlane = lane >> 5;          // 0/1
    const int dq = (lane & 31) * 4;       // 0..124
    float4 x[TIB], acc[TIB];
#pragma unroll
    for (int r = 0; r < TIB; ++r) {
        x[r] = *reinterpret_cast<const float4*>(&ai[(size_t)(r0 + r) * Dc + dq]);
        acc[r] = make_float4(0.f, 0.f, 0.f, 0.f);
    }
    __syncthreads();

    // ---- stream: 32 iters x (1 float4 VMEM + 4 LDS b32 + 48 VALU)
    const int jw = w * 64;
    const float* __restrict__ pbase = ajb + (size_t)(jw + jlane) * Dc + dq;
#pragma unroll 4
    for (int it = 0; it < 32; ++it) {
        const float4 v = *reinterpret_cast<const float4*>(pbase + (size_t)it * 256);
        const int j = jw + 2 * it + jlane;
        const float a0 = adjs[0][j];
        const float a1 = adjs[1][j];
        const float a2 = adjs[2][j];
        const float a3 = adjs[3][j];
#define ROWF(r, a)                                                       \
        acc[r].x = fmaf(a, fmaxf(x[r].x + v.x, 0.f), acc[r].x);          \
        acc[r].y = fmaf(a, fmaxf(x[r].y + v.y, 0.f), acc[r].y);          \
        acc[r].z = fmaf(a, fmaxf(x[r].z + v.z, 0.f), acc[r].z);          \
        acc[r].w = fmaf(a, fmaxf(x[r].w + v.w, 0.f), acc[r].w);
        ROWF(0, a0) ROWF(1, a1) ROWF(2, a2) ROWF(3, a3)
#undef ROWF
    }

    // ---- merge j-parity halves, park per-wave partials in scratch
#pragma unroll
    for (int r = 0; r < TIB; ++r) {
        acc[r].x += __shfl_xor(acc[r].x, 32);
        acc[r].y += __shfl_xor(acc[r].y, 32);
        acc[r].z += __shfl_xor(acc[r].z, 32);
        acc[r].w += __shfl_xor(acc[r].w, 32);
    }
    if (lane < 32) {
#pragma unroll
        for (int r = 0; r < TIB; ++r)
            *reinterpret_cast<float4*>(&scratch[w * 512 + r * 128 + dq]) = acc[r];
    }
    __syncthreads();

    // ---- reduce 8 wave-partials -> s_lds
    {
        const int rr = tid >> 7;
        const int dd = tid & 127;
        float s = 0.f;
#pragma unroll
        for (int ww = 0; ww < 8; ++ww) s += scratch[ww * 512 + rr * 128 + dd];
        s_lds[rr][dd] = s;
    }
    __syncthreads();

    // ---- lin2 GEMV, d-sliced: thread (o, g) does d in [g*32, g*32+32)
    {
        const int o = tid & 127;
        const int g = tid >> 7;
        float part[TIB] = {0.f, 0.f, 0.f, 0.f};
        for (int dd = g * 32; dd < g * 32 + 32; dd += 4) {
            float wv[4];
#pragma unroll
            for (int k = 0; k < 4; ++k) wv[k] = w2T[(size_t)(dd + k) * Dc + o];
#pragma unroll
            for (int r = 0; r < TIB; ++r) {
                const float4 sv = *reinterpret_cast<const float4*>(&s_lds[r][dd]);
                part[r] = fmaf(sv.x, wv[0], part[r]);
                part[r] = fmaf(sv.y, wv[1], part[r]);
                part[r] = fmaf(sv.z, wv[2], part[r]);
                part[r] = fmaf(sv.w, wv[3], part[r]);
            }
        }
#pragma unroll
        for (int r = 0; r < TIB; ++r) scratch[g * 512 + r * 128 + o] = part[r];
    }
    __syncthreads();

    // ---- combine partials + residual + b2*arow -> hnew
    {
        const int rr = tid >> 7;
        const int o = tid & 127;
        float a2c = scratch[rr * 128 + o] + scratch[512 + rr * 128 + o] +
                    scratch[1024 + rr * 128 + o] + scratch[1536 + rr * 128 + o];
        const float arow_r = redw[2 * rr] + redw[2 * rr + 1];
        const float hn =
            hin[(size_t)(r0 + rr) * Dc + o] + a2c + arow_r * b2[o];
        hout[(size_t)(r0 + rr) * Dc + o] = hn;
        if constexpr (HAS_NEXT) hnew_lds[rr][o] = hn;
    }

    if constexpr (HAS_NEXT) {
        __syncthreads();
        // ---- lin1 of next layer (wi and wj GEMVs), d-sliced
        {
            const int o = tid & 127;
            const int g = tid >> 7;
            float pi[TIB] = {0.f, 0.f, 0.f, 0.f};
            float pj[TIB] = {0.f, 0.f, 0.f, 0.f};
            for (int dd = g * 32; dd < g * 32 + 32; dd += 4) {
                float wiv[4], wjv[4];
#pragma unroll
                for (int k = 0; k < 4; ++k) {
                    wiv[k] = wiT[(size_t)(dd + k) * Dc + o];
                    wjv[k] = wjT[(size_t)(dd + k) * Dc + o];
                }
#pragma unroll
                for (int r = 0; r < TIB; ++r) {
                    const float4 hv =
                        *reinterpret_cast<const float4*>(&hnew_lds[r][dd]);
                    pi[r] = fmaf(hv.x, wiv[0], pi[r]);
                    pi[r] = fmaf(hv.y, wiv[1], pi[r]);
                    pi[r] = fmaf(hv.z, wiv[2], pi[r]);
                    pi[r] = fmaf(hv.w, wiv[3], pi[r]);
                    pj[r] = fmaf(hv.x, wjv[0], pj[r]);
                    pj[r] = fmaf(hv.y, wjv[1], pj[r]);
                    pj[r] = fmaf(hv.z, wjv[2], pj[r]);
                    pj[r] = fmaf(hv.w, wjv[3], pj[r]);
                }
            }
#pragma unroll
            for (int r = 0; r < TIB; ++r) {
                scratch[g * 512 + r * 128 + o] = pi[r];
                scratch[2048 + g * 512 + r * 128 + o] = pj[r];
            }
        }
        __syncthreads();
        {
            const int rr = tid >> 7;
            const int o = tid & 127;
            float acci = b1[o];
            float accj = 0.f;
#pragma unroll
            for (int g = 0; g < 4; ++g) {
                acci += scratch[g * 512 + rr * 128 + o];
                accj += scratch[2048 + g * 512 + rr * 128 + o];
            }
            ai_out[(size_t)(r0 + rr) * Dc + o] = acci;
            aj_out[(size_t)(r0 + rr) * Dc + o] = accj;
        }
    }
}

extern "C" void kernel_launch(void* const* d_in, const int* in_sizes, int n_in,
                              void* d_out, int out_size, void* d_ws, size_t ws_size,
                              hipStream_t stream) {
    const float* node = (const float*)d_in[0];
    const float* adj  = (const float*)d_in[1];
    const float* w1   = (const float*)d_in[2];
    const float* b1   = (const float*)d_in[3];
    const float* w2   = (const float*)d_in[4];
    const float* b2   = (const float*)d_in[5];
    float* out = (float*)d_out;

    float* ws = (float*)d_ws;
    float* wiT = ws; ws += Lc * Dc * Dc;
    float* wjT = ws; ws += Lc * Dc * Dc;
    float* w2T = ws; ws += Lc * Dc * Dc;
    float* ai  = ws; ws += BN * Dc;
    float* aj  = ws; ws += BN * Dc;
    float* ai2 = ws; ws += BN * Dc;
    float* aj2 = ws; ws += BN * Dc;
    float* h1  = ws; ws += BN * Dc;

    // dispatch 1: lin1(L0, natural w1) + transpose rider blocks
    gnn_lin1_trans<<<BN / TN + TBLK, 128, 0, stream>>>(node, w1, b1, w2, ai, aj,
                                                       wiT, wjT, w2T);
    // dispatch 2: L0 msg + lin2 + residual, fused lin1(L1)
    gnn_msgfull<true><<<BN / TIB, 512, 0, stream>>>(
        ai, aj, adj, node, w2T, b2, wiT + Dc * Dc, wjT + Dc * Dc, b1 + Dc,
        h1, ai2, aj2);
    // dispatch 3: L1 msg + lin2 + residual -> out
    gnn_msgfull<false><<<BN / TIB, 512, 0, stream>>>(
        ai2, aj2, adj, h1, w2T + Dc * Dc, b2 + Dc, nullptr, nullptr, nullptr,
        out, nullptr, nullptr);
}

// Round 16
// 48.181 us; speedup vs baseline: 1.1766x; 1.0011x over previous
//
#include <hip/hip_runtime.h>

// SimpleGNN: B=4, N=512, D=128, L=2 — 3 dispatches. CONFIRMATION RUN of the
// round-15 best (48.2us): byte-identical resubmit to establish the plateau
// against the measured +/-4us cross-round noise band.
// msg[b,i,:] = (sum_j adj[b,i,j]*relu(ai'[b,i,:]+aj[b,j,:])) @ w2^T
//            + (sum_j adj[b,i,j]) * b2 ;  ai' = h@wi^T + b1, aj = h@wj^T
// Structure: D1 = lin1(L0, natural w1) + transpose riders; D2 = msg(L0) +
// lin2 + residual + lin1(L1); D3 = msg(L1) + lin2 + residual -> out.

constexpr int Bc = 4, Nc = 512, Dc = 128, Lc = 2;
constexpr int BN = Bc * Nc;  // 2048
constexpr int TIB = 4;       // rows per msgfull block
constexpr int TN = 4;        // rows per lin block
constexpr int TBLK = 64;     // transpose rider blocks (128 thr each)

// --- combined: blocks [0,512) = lin1 layer 0 (natural w1 reads);
//               blocks [512,576) = transpose wiT/wjT/w2T for later dispatches.
__global__ __launch_bounds__(128) void gnn_lin1_trans(
    const float* __restrict__ node, const float* __restrict__ w1,
    const float* __restrict__ b1, const float* __restrict__ w2,
    float* __restrict__ ai, float* __restrict__ aj, float* __restrict__ wiT,
    float* __restrict__ wjT, float* __restrict__ w2T) {
    const int blk = blockIdx.x;
    if (blk < BN / TN) {
        // ---- lin1, natural-layout weights (thread o streams w1 row o)
        __shared__ float hs[TN][Dc];
        const int o = threadIdx.x;
        const int r0 = blk * TN;
#pragma unroll
        for (int t = 0; t < TN; ++t) hs[t][o] = node[(size_t)(r0 + t) * Dc + o];
        __syncthreads();
        float acci[TN], accj[TN];
        const float bo = b1[o];
#pragma unroll
        for (int t = 0; t < TN; ++t) { acci[t] = bo; accj[t] = 0.f; }
        const float* __restrict__ w1row = w1 + (size_t)o * (2 * Dc);
        for (int d = 0; d < Dc; d += 4) {
            const float4 wi = *reinterpret_cast<const float4*>(&w1row[d]);
            const float4 wj = *reinterpret_cast<const float4*>(&w1row[Dc + d]);
#pragma unroll
            for (int t = 0; t < TN; ++t) {
                const float4 hv = *reinterpret_cast<const float4*>(&hs[t][d]);
                acci[t] = fmaf(hv.x, wi.x, acci[t]);
                acci[t] = fmaf(hv.y, wi.y, acci[t]);
                acci[t] = fmaf(hv.z, wi.z, acci[t]);
                acci[t] = fmaf(hv.w, wi.w, acci[t]);
                accj[t] = fmaf(hv.x, wj.x, accj[t]);
                accj[t] = fmaf(hv.y, wj.y, accj[t]);
                accj[t] = fmaf(hv.z, wj.z, accj[t]);
                accj[t] = fmaf(hv.w, wj.w, accj[t]);
            }
        }
#pragma unroll
        for (int t = 0; t < TN; ++t) {
            ai[(size_t)(r0 + t) * Dc + o] = acci[t];
            aj[(size_t)(r0 + t) * Dc + o] = accj[t];
        }
    } else {
        // ---- transpose rider: wiT/wjT/w2T [l][d][o] <- w1/w2 [l][o][*]
        const int base = (blk - BN / TN) * 128 + threadIdx.x;  // 0..8191
        for (int idx = base; idx < Lc * Dc * Dc; idx += TBLK * 128) {
            const int l = idx >> 14;
            const int rem = idx & (Dc * Dc - 1);
            const int d = rem >> 7;
            const int o = rem & 127;
            wiT[idx] = w1[(size_t)(l * Dc + o) * (2 * Dc) + d];
            wjT[idx] = w1[(size_t)(l * Dc + o) * (2 * Dc) + Dc + d];
            w2T[idx] = w2[(size_t)(l * Dc + o) * Dc + d];
        }
    }
}

// --- fused msg + lin2 + residual (+ lin1 of next layer) — round-9 verbatim.
// grid = BN/TIB = 512 blocks, 512 thr (8 waves). Wave w streams j in
// [w*64, w*64+64) as 32 float4 loads (2 j's each).
template <bool HAS_NEXT>
__global__ __launch_bounds__(512) void gnn_msgfull(
    const float* __restrict__ ai, const float* __restrict__ aj,
    const float* __restrict__ adj, const float* __restrict__ hin,
    const float* __restrict__ w2T, const float* __restrict__ b2,
    const float* __restrict__ wiT, const float* __restrict__ wjT,
    const float* __restrict__ b1, float* __restrict__ hout,
    float* __restrict__ ai_out, float* __restrict__ aj_out) {
    __shared__ __align__(16) float adjs[TIB][Nc];   // 8 KB  [r][j]
    __shared__ __align__(16) float scratch[4096];   // 16 KB
    __shared__ float s_lds[TIB][Dc];                // 2 KB
    __shared__ float hnew_lds[TIB][Dc];             // 2 KB
    __shared__ float redw[8];

    const int tid = threadIdx.x;
    const int w = tid >> 6;
    const int lane = tid & 63;
    const int r0 = blockIdx.x * TIB;
    const int b = r0 >> 9;        // / Nc
    const int i0 = r0 & (Nc - 1);
    const float* __restrict__ ajb = aj + (size_t)b * Nc * Dc;
    const float* __restrict__ adjb = adj + (size_t)b * Nc * Nc;

    // ---- stage adjs [r][j] (coalesced) + arow wave partials
    {
        const int rr = tid >> 7;          // 0..3
        const int c4 = (tid & 127) * 4;
        const float4 av =
            *reinterpret_cast<const float4*>(&adjb[(size_t)(i0 + rr) * Nc + c4]);
        *reinterpret_cast<float4*>(&adjs[rr][c4]) = av;
        float p = av.x + av.y + av.z + av.w;
#pragma unroll
        for (int m = 32; m >= 1; m >>= 1) p += __shfl_xor(p, m);
        if (lane == 0) redw[w] = p;       // row (w>>1), col-half (w&1)
    }

    // ---- per-lane stream state: j-parity jlane, d-quad dq
    const int jlane = lane >> 5;          // 0/1
    const int dq = (lane & 31) * 4;       // 0..124
    float4 x[TIB], acc[TIB];
#pragma unroll
    for (int r = 0; r < TIB; ++r) {
        x[r] = *reinterpret_cast<const float4*>(&ai[(size_t)(r0 + r) * Dc + dq]);
        acc[r] = make_float4(0.f, 0.f, 0.f, 0.f);
    }
    __syncthreads();

    // ---- stream: 32 iters x (1 float4 VMEM + 4 LDS b32 + 48 VALU)
    const int jw = w * 64;
    const float* __restrict__ pbase = ajb + (size_t)(jw + jlane) * Dc + dq;
#pragma unroll 4
    for (int it = 0; it < 32; ++it) {
        const float4 v = *reinterpret_cast<const float4*>(pbase + (size_t)it * 256);
        const int j = jw + 2 * it + jlane;
        const float a0 = adjs[0][j];
        const float a1 = adjs[1][j];
        const float a2 = adjs[2][j];
        const float a3 = adjs[3][j];
#define ROWF(r, a)                                                       \
        acc[r].x = fmaf(a, fmaxf(x[r].x + v.x, 0.f), acc[r].x);          \
        acc[r].y = fmaf(a, fmaxf(x[r].y + v.y, 0.f), acc[r].y);          \
        acc[r].z = fmaf(a, fmaxf(x[r].z + v.z, 0.f), acc[r].z);          \
        acc[r].w = fmaf(a, fmaxf(x[r].w + v.w, 0.f), acc[r].w);
        ROWF(0, a0) ROWF(1, a1) ROWF(2, a2) ROWF(3, a3)
#undef ROWF
    }

    // ---- merge j-parity halves, park per-wave partials in scratch
#pragma unroll
    for (int r = 0; r < TIB; ++r) {
        acc[r].x += __shfl_xor(acc[r].x, 32);
        acc[r].y += __shfl_xor(acc[r].y, 32);
        acc[r].z += __shfl_xor(acc[r].z, 32);
        acc[r].w += __shfl_xor(acc[r].w, 32);
    }
    if (lane < 32) {
#pragma unroll
        for (int r = 0; r < TIB; ++r)
            *reinterpret_cast<float4*>(&scratch[w * 512 + r * 128 + dq]) = acc[r];
    }
    __syncthreads();

    // ---- reduce 8 wave-partials -> s_lds
    {
        const int rr = tid >> 7;
        const int dd = tid & 127;
        float s = 0.f;
#pragma unroll
        for (int ww = 0; ww < 8; ++ww) s += scratch[ww * 512 + rr * 128 + dd];
        s_lds[rr][dd] = s;
    }
    __syncthreads();

    // ---- lin2 GEMV, d-sliced: thread (o, g) does d in [g*32, g*32+32)
    {
        const int o = tid & 127;
        const int g = tid >> 7;
        float part[TIB] = {0.f, 0.f, 0.f, 0.f};
        for (int dd = g * 32; dd < g * 32 + 32; dd += 4) {
            float wv[4];
#pragma unroll
            for (int k = 0; k < 4; ++k) wv[k] = w2T[(size_t)(dd + k) * Dc + o];
#pragma unroll
            for (int r = 0; r < TIB; ++r) {
                const float4 sv = *reinterpret_cast<const float4*>(&s_lds[r][dd]);
                part[r] = fmaf(sv.x, wv[0], part[r]);
                part[r] = fmaf(sv.y, wv[1], part[r]);
                part[r] = fmaf(sv.z, wv[2], part[r]);
                part[r] = fmaf(sv.w, wv[3], part[r]);
            }
        }
#pragma unroll
        for (int r = 0; r < TIB; ++r) scratch[g * 512 + r * 128 + o] = part[r];
    }
    __syncthreads();

    // ---- combine partials + residual + b2*arow -> hnew
    {
        const int rr = tid >> 7;
        const int o = tid & 127;
        float a2c = scratch[rr * 128 + o] + scratch[512 + rr * 128 + o] +
                    scratch[1024 + rr * 128 + o] + scratch[1536 + rr * 128 + o];
        const float arow_r = redw[2 * rr] + redw[2 * rr + 1];
        const float hn =
            hin[(size_t)(r0 + rr) * Dc + o] + a2c + arow_r * b2[o];
        hout[(size_t)(r0 + rr) * Dc + o] = hn;
        if constexpr (HAS_NEXT) hnew_lds[rr][o] = hn;
    }

    if constexpr (HAS_NEXT) {
        __syncthreads();
        // ---- lin1 of next layer (wi and wj GEMVs), d-sliced
        {
            const int o = tid & 127;
            const int g = tid >> 7;
            float pi[TIB] = {0.f, 0.f, 0.f, 0.f};
            float pj[TIB] = {0.f, 0.f, 0.f, 0.f};
            for (int dd = g * 32; dd < g * 32 + 32; dd += 4) {
                float wiv[4], wjv[4];
#pragma unroll
                for (int k = 0; k < 4; ++k) {
                    wiv[k] = wiT[(size_t)(dd + k) * Dc + o];
                    wjv[k] = wjT[(size_t)(dd + k) * Dc + o];
                }
#pragma unroll
                for (int r = 0; r < TIB; ++r) {
                    const float4 hv =
                        *reinterpret_cast<const float4*>(&hnew_lds[r][dd]);
                    pi[r] = fmaf(hv.x, wiv[0], pi[r]);
                    pi[r] = fmaf(hv.y, wiv[1], pi[r]);
                    pi[r] = fmaf(hv.z, wiv[2], pi[r]);
                    pi[r] = fmaf(hv.w, wiv[3], pi[r]);
                    pj[r] = fmaf(hv.x, wjv[0], pj[r]);
                    pj[r] = fmaf(hv.y, wjv[1], pj[r]);
                    pj[r] = fmaf(hv.z, wjv[2], pj[r]);
                    pj[r] = fmaf(hv.w, wjv[3], pj[r]);
                }
            }
#pragma unroll
            for (int r = 0; r < TIB; ++r) {
                scratch[g * 512 + r * 128 + o] = pi[r];
                scratch[2048 + g * 512 + r * 128 + o] = pj[r];
            }
        }
        __syncthreads();
        {
            const int rr = tid >> 7;
            const int o = tid & 127;
            float acci = b1[o];
            float accj = 0.f;
#pragma unroll
            for (int g = 0; g < 4; ++g) {
                acci += scratch[g * 512 + rr * 128 + o];
                accj += scratch[2048 + g * 512 + rr * 128 + o];
            }
            ai_out[(size_t)(r0 + rr) * Dc + o] = acci;
            aj_out[(size_t)(r0 + rr) * Dc + o] = accj;
        }
    }
}

extern "C" void kernel_launch(void* const* d_in, const int* in_sizes, int n_in,
                              void* d_out, int out_size, void* d_ws, size_t ws_size,
                              hipStream_t stream) {
    const float* node = (const float*)d_in[0];
    const float* adj  = (const float*)d_in[1];
    const float* w1   = (const float*)d_in[2];
    const float* b1   = (const float*)d_in[3];
    const float* w2   = (const float*)d_in[4];
    const float* b2   = (const float*)d_in[5];
    float* out = (float*)d_out;

    float* ws = (float*)d_ws;
    float* wiT = ws; ws += Lc * Dc * Dc;
    float* wjT = ws; ws += Lc * Dc * Dc;
    float* w2T = ws; ws += Lc * Dc * Dc;
    float* ai  = ws; ws += BN * Dc;
    float* aj  = ws; ws += BN * Dc;
    float* ai2 = ws; ws += BN * Dc;
    float* aj2 = ws; ws += BN * Dc;
    float* h1  = ws; ws += BN * Dc;

    // dispatch 1: lin1(L0, natural w1) + transpose rider blocks
    gnn_lin1_trans<<<BN / TN + TBLK, 128, 0, stream>>>(node, w1, b1, w2, ai, aj,
                                                       wiT, wjT, w2T);
    // dispatch 2: L0 msg + lin2 + residual, fused lin1(L1)
    gnn_msgfull<true><<<BN / TIB, 512, 0, stream>>>(
        ai, aj, adj, node, w2T, b2, wiT + Dc * Dc, wjT + Dc * Dc, b1 + Dc,
        h1, ai2, aj2);
    // dispatch 3: L1 msg + lin2 + residual -> out
    gnn_msgfull<false><<<BN / TIB, 512, 0, stream>>>(
        ai2, aj2, adj, h1, w2T + Dc * Dc, b2 + Dc, nullptr, nullptr, nullptr,
        out, nullptr, nullptr);
}